// Round 1
// baseline (438.016 us; speedup 1.0000x reference)
//
#include <hip/hip_runtime.h>

// ---------- constants ----------
#define BATCH 4
#define SEQ   2048
#define NHEAD 8
#define DQKV  64
#define DMODEL 512
#define ROWS  (BATCH*SEQ)          // 8192
#define BH    (BATCH*NHEAD)        // 32
#define HSTRIDE (SEQ*DQKV)         // 131072 elements per (b,h)

using f32x4  = __attribute__((ext_vector_type(4))) float;
using short8 = __attribute__((ext_vector_type(8))) short;

__device__ inline short f2bf(float f) {
    unsigned u = __float_as_uint(f);
    u += 0x7FFFu + ((u >> 16) & 1u);
    return (short)(u >> 16);
}

// ---------- prep: layernorm q -> bf16 ----------
__global__ __launch_bounds__(256) void ln_cast_kernel(
        const float* __restrict__ q, const float* __restrict__ gamma,
        const float* __restrict__ beta, short* __restrict__ qn) {
    int wave = threadIdx.x >> 6;
    int lane = threadIdx.x & 63;
    int row  = blockIdx.x * 4 + wave;            // 8192 rows
    const float4* qr = (const float4*)(q + (size_t)row * DMODEL);
    float4 x0 = qr[lane * 2];
    float4 x1 = qr[lane * 2 + 1];
    float s  = x0.x + x0.y + x0.z + x0.w + x1.x + x1.y + x1.z + x1.w;
    float s2 = x0.x*x0.x + x0.y*x0.y + x0.z*x0.z + x0.w*x0.w
             + x1.x*x1.x + x1.y*x1.y + x1.z*x1.z + x1.w*x1.w;
    #pragma unroll
    for (int m = 1; m < 64; m <<= 1) {
        s  += __shfl_xor(s,  m);
        s2 += __shfl_xor(s2, m);
    }
    float mu  = s * (1.0f / DMODEL);
    float var = s2 * (1.0f / DMODEL) - mu * mu;
    float rstd = rsqrtf(var + 1e-6f);
    const float4* g = (const float4*)gamma;
    const float4* be = (const float4*)beta;
    float4 g0 = g[lane*2], g1 = g[lane*2+1];
    float4 b0 = be[lane*2], b1 = be[lane*2+1];
    short8 o;
    o[0] = f2bf((x0.x - mu) * rstd * g0.x + b0.x);
    o[1] = f2bf((x0.y - mu) * rstd * g0.y + b0.y);
    o[2] = f2bf((x0.z - mu) * rstd * g0.z + b0.z);
    o[3] = f2bf((x0.w - mu) * rstd * g0.w + b0.w);
    o[4] = f2bf((x1.x - mu) * rstd * g1.x + b1.x);
    o[5] = f2bf((x1.y - mu) * rstd * g1.y + b1.y);
    o[6] = f2bf((x1.z - mu) * rstd * g1.z + b1.z);
    o[7] = f2bf((x1.w - mu) * rstd * g1.w + b1.w);
    ((short8*)(qn + (size_t)row * DMODEL))[lane] = o;
}

// ---------- prep: fp32 -> bf16 elementwise (8/thread) ----------
__global__ __launch_bounds__(256) void cast_bf16_kernel(
        const float* __restrict__ in, short* __restrict__ out) {
    size_t i = ((size_t)blockIdx.x * blockDim.x + threadIdx.x) * 8;
    float4 a = *(const float4*)(in + i);
    float4 b = *(const float4*)(in + i + 4);
    short8 o;
    o[0]=f2bf(a.x); o[1]=f2bf(a.y); o[2]=f2bf(a.z); o[3]=f2bf(a.w);
    o[4]=f2bf(b.x); o[5]=f2bf(b.y); o[6]=f2bf(b.z); o[7]=f2bf(b.w);
    *(short8*)(out + i) = o;
}

// ---------- prep: W[k][n] fp32 -> Wt[n][k] bf16 ----------
__global__ __launch_bounds__(256) void castWT_kernel(
        const float* __restrict__ W, short* __restrict__ Wt) {
    int idx = blockIdx.x * 256 + threadIdx.x;   // 262144
    int kk = idx >> 9, n = idx & 511;
    Wt[n * DMODEL + kk] = f2bf(W[idx]);
}

// ---------- QKV projection GEMM ----------
// A: [8192][512] bf16 row-major; Wt: [512][512] bf16 (n-major);
// out: [B][H][S][64] bf16, value = (A@W)[m][n]*scale
__global__ __launch_bounds__(256) void proj_kernel(
        const short* __restrict__ A, const short* __restrict__ Wt,
        short* __restrict__ outh, float scale) {
    int tid = threadIdx.x;
    int wave = tid >> 6, lane = tid & 63;
    int wr = wave >> 1, wc = wave & 1;
    int RB = blockIdx.x * 64 + wr * 32;
    int CB = blockIdx.y * 64 + wc * 32;
    int lm = lane & 15, lg = lane >> 4;
    f32x4 acc00{}, acc01{}, acc10{}, acc11{};
    const short8* Ar0 = (const short8*)(A + (size_t)(RB + lm) * DMODEL);
    const short8* Ar1 = (const short8*)(A + (size_t)(RB + 16 + lm) * DMODEL);
    const short8* Br0 = (const short8*)(Wt + (size_t)(CB + lm) * DMODEL);
    const short8* Br1 = (const short8*)(Wt + (size_t)(CB + 16 + lm) * DMODEL);
    #pragma unroll 4
    for (int kk = 0; kk < DMODEL; kk += 32) {
        int ko = (kk >> 3) + lg;
        short8 a0 = Ar0[ko], a1 = Ar1[ko];
        short8 b0 = Br0[ko], b1 = Br1[ko];
        acc00 = __builtin_amdgcn_mfma_f32_16x16x32_bf16(a0, b0, acc00, 0, 0, 0);
        acc01 = __builtin_amdgcn_mfma_f32_16x16x32_bf16(a0, b1, acc01, 0, 0, 0);
        acc10 = __builtin_amdgcn_mfma_f32_16x16x32_bf16(a1, b0, acc10, 0, 0, 0);
        acc11 = __builtin_amdgcn_mfma_f32_16x16x32_bf16(a1, b1, acc11, 0, 0, 0);
    }
    f32x4 accs[2][2] = {{acc00, acc01}, {acc10, acc11}};
    #pragma unroll
    for (int i = 0; i < 2; ++i) {
        #pragma unroll
        for (int j = 0; j < 2; ++j) {
            int n = CB + j * 16 + lm;
            int h = n >> 6, d = n & 63;
            #pragma unroll
            for (int r = 0; r < 4; ++r) {
                int m = RB + i * 16 + lg * 4 + r;
                int b = m >> 11, s = m & 2047;
                outh[(size_t)(b * NHEAD + h) * HSTRIDE + (size_t)s * DQKV + d] =
                    f2bf(accs[i][j][r] * scale);
            }
        }
    }
}

// ---------- flash attention ----------
// qh/kh/vh: [B][H][S][64] bf16 (qh pre-scaled by 1/8); mask: [B][S][S] int32
// oh: [B][H][S][64] bf16
__global__ __launch_bounds__(256) void attn_kernel(
        const short* __restrict__ qh, const short* __restrict__ kh,
        const short* __restrict__ vh, const int* __restrict__ mask,
        short* __restrict__ oh) {
    __shared__ short Kl[64 * 72];
    __shared__ short Vt[64 * 72];
    __shared__ short Pl[4 * 16 * 72];
    int tid = threadIdx.x, wave = tid >> 6, lane = tid & 63;
    int lm = lane & 15, lg = lane >> 4;
    int qt = blockIdx.x, bh = blockIdx.y;
    int b = bh >> 3;
    const short* Kbase = kh + (size_t)bh * HSTRIDE;
    const short* Vbase = vh + (size_t)bh * HSTRIDE;
    int qbase = qt * 64 + wave * 16;

    const short8* Qrow = (const short8*)(qh + (size_t)bh * HSTRIDE + (size_t)(qbase + lm) * DQKV);
    short8 aq0 = Qrow[lg];
    short8 aq1 = Qrow[lg + 4];

    f32x4 o0{}, o1{}, o2{}, o3{};
    float mrow[4], lrow[4];
    #pragma unroll
    for (int r = 0; r < 4; ++r) { mrow[r] = -INFINITY; lrow[r] = 0.0f; }

    const int* maskbase = mask + (size_t)(b * SEQ + qbase + lg * 4) * SEQ + lm;

    int skey  = tid >> 2;      // staging: key 0..63
    int sdseg = tid & 3;       // d-segment 0..3

    for (int kt = 0; kt < SEQ; kt += 64) {
        // stage K tile [key][d] and V tile transposed [d][key]
        {
            const short8* src = (const short8*)(Kbase + (size_t)(kt + skey) * DQKV);
            short8* dst = (short8*)(Kl + skey * 72);
            dst[sdseg]     = src[sdseg];
            dst[sdseg + 4] = src[sdseg + 4];
            const short8* vs = (const short8*)(Vbase + (size_t)(kt + skey) * DQKV);
            short8 v0 = vs[sdseg], v1 = vs[sdseg + 4];
            #pragma unroll
            for (int j = 0; j < 8; ++j) Vt[(sdseg * 8 + j) * 72 + skey] = v0[j];
            #pragma unroll
            for (int j = 0; j < 8; ++j) Vt[(32 + sdseg * 8 + j) * 72 + skey] = v1[j];
        }
        __syncthreads();

        // S = Q K^T  (16 queries x 64 keys per wave)
        f32x4 sk[4];
        #pragma unroll
        for (int kg = 0; kg < 4; ++kg) {
            short8 bk0 = *(const short8*)(Kl + (kg * 16 + lm) * 72 + lg * 8);
            short8 bk1 = *(const short8*)(Kl + (kg * 16 + lm) * 72 + 32 + lg * 8);
            f32x4 z{};
            z = __builtin_amdgcn_mfma_f32_16x16x32_bf16(aq0, bk0, z, 0, 0, 0);
            sk[kg] = __builtin_amdgcn_mfma_f32_16x16x32_bf16(aq1, bk1, z, 0, 0, 0);
        }

        // mask
        #pragma unroll
        for (int kg = 0; kg < 4; ++kg) {
            #pragma unroll
            for (int r = 0; r < 4; ++r) {
                int mv = maskbase[(size_t)r * SEQ + kt + kg * 16];
                sk[kg][r] = mv ? sk[kg][r] : -1e9f;
            }
        }

        // online softmax
        float nm[4];
        #pragma unroll
        for (int r = 0; r < 4; ++r)
            nm[r] = fmaxf(fmaxf(sk[0][r], sk[1][r]), fmaxf(sk[2][r], sk[3][r]));
        #pragma unroll
        for (int m = 1; m < 16; m <<= 1) {
            #pragma unroll
            for (int r = 0; r < 4; ++r) nm[r] = fmaxf(nm[r], __shfl_xor(nm[r], m));
        }
        float alpha[4];
        #pragma unroll
        for (int r = 0; r < 4; ++r) {
            float mn = fmaxf(mrow[r], nm[r]);
            alpha[r] = __expf(mrow[r] - mn);
            mrow[r] = mn;
        }
        #pragma unroll
        for (int kg = 0; kg < 4; ++kg) {
            #pragma unroll
            for (int r = 0; r < 4; ++r) sk[kg][r] = __expf(sk[kg][r] - mrow[r]);
        }
        float rsum[4];
        #pragma unroll
        for (int r = 0; r < 4; ++r)
            rsum[r] = sk[0][r] + sk[1][r] + sk[2][r] + sk[3][r];
        #pragma unroll
        for (int m = 1; m < 16; m <<= 1) {
            #pragma unroll
            for (int r = 0; r < 4; ++r) rsum[r] += __shfl_xor(rsum[r], m);
        }
        #pragma unroll
        for (int r = 0; r < 4; ++r) {
            lrow[r] = lrow[r] * alpha[r] + rsum[r];
            o0[r] *= alpha[r]; o1[r] *= alpha[r]; o2[r] *= alpha[r]; o3[r] *= alpha[r];
        }

        // P (C-layout) -> LDS -> A-layout
        short* Pw = Pl + wave * 16 * 72;
        #pragma unroll
        for (int kg = 0; kg < 4; ++kg) {
            #pragma unroll
            for (int r = 0; r < 4; ++r)
                Pw[(lg * 4 + r) * 72 + kg * 16 + lm] = f2bf(sk[kg][r]);
        }
        __syncthreads();

        short8 ap0 = *(const short8*)(Pw + lm * 72 + lg * 8);
        short8 ap1 = *(const short8*)(Pw + lm * 72 + 32 + lg * 8);
        {
            short8 bv0 = *(const short8*)(Vt + (0 * 16 + lm) * 72 + lg * 8);
            short8 bv1 = *(const short8*)(Vt + (0 * 16 + lm) * 72 + 32 + lg * 8);
            o0 = __builtin_amdgcn_mfma_f32_16x16x32_bf16(ap0, bv0, o0, 0, 0, 0);
            o0 = __builtin_amdgcn_mfma_f32_16x16x32_bf16(ap1, bv1, o0, 0, 0, 0);
        }
        {
            short8 bv0 = *(const short8*)(Vt + (1 * 16 + lm) * 72 + lg * 8);
            short8 bv1 = *(const short8*)(Vt + (1 * 16 + lm) * 72 + 32 + lg * 8);
            o1 = __builtin_amdgcn_mfma_f32_16x16x32_bf16(ap0, bv0, o1, 0, 0, 0);
            o1 = __builtin_amdgcn_mfma_f32_16x16x32_bf16(ap1, bv1, o1, 0, 0, 0);
        }
        {
            short8 bv0 = *(const short8*)(Vt + (2 * 16 + lm) * 72 + lg * 8);
            short8 bv1 = *(const short8*)(Vt + (2 * 16 + lm) * 72 + 32 + lg * 8);
            o2 = __builtin_amdgcn_mfma_f32_16x16x32_bf16(ap0, bv0, o2, 0, 0, 0);
            o2 = __builtin_amdgcn_mfma_f32_16x16x32_bf16(ap1, bv1, o2, 0, 0, 0);
        }
        {
            short8 bv0 = *(const short8*)(Vt + (3 * 16 + lm) * 72 + lg * 8);
            short8 bv1 = *(const short8*)(Vt + (3 * 16 + lm) * 72 + 32 + lg * 8);
            o3 = __builtin_amdgcn_mfma_f32_16x16x32_bf16(ap0, bv0, o3, 0, 0, 0);
            o3 = __builtin_amdgcn_mfma_f32_16x16x32_bf16(ap1, bv1, o3, 0, 0, 0);
        }
        __syncthreads();
    }

    // epilogue: divide by l, store bf16 [b][h][q][d]
    short* obase = oh + (size_t)bh * HSTRIDE;
    f32x4 oo[4] = {o0, o1, o2, o3};
    #pragma unroll
    for (int dt = 0; dt < 4; ++dt) {
        #pragma unroll
        for (int r = 0; r < 4; ++r) {
            float val = oo[dt][r] / lrow[r];
            obase[(size_t)(qbase + lg * 4 + r) * DQKV + dt * 16 + lm] = f2bf(val);
        }
    }
}

// ---------- output projection + residual ----------
// Ah: [B][H][S][64] bf16; Wfct: [512][512] bf16 (n-major); resid: q fp32; out fp32
__global__ __launch_bounds__(256) void outproj_kernel(
        const short* __restrict__ Ah, const short* __restrict__ Wfct,
        const float* __restrict__ resid, float* __restrict__ out) {
    int tid = threadIdx.x;
    int wave = tid >> 6, lane = tid & 63;
    int wr = wave >> 1, wc = wave & 1;
    int RB = blockIdx.x * 64 + wr * 32;
    int CB = blockIdx.y * 64 + wc * 32;
    int lm = lane & 15, lg = lane >> 4;

    int m0 = RB + lm, m1 = RB + 16 + lm;
    size_t rb0 = (size_t)(m0 >> 11) * (NHEAD * HSTRIDE) + (size_t)(m0 & 2047) * DQKV;
    size_t rb1 = (size_t)(m1 >> 11) * (NHEAD * HSTRIDE) + (size_t)(m1 & 2047) * DQKV;
    const short8* Br0 = (const short8*)(Wfct + (size_t)(CB + lm) * DMODEL);
    const short8* Br1 = (const short8*)(Wfct + (size_t)(CB + 16 + lm) * DMODEL);

    f32x4 acc00{}, acc01{}, acc10{}, acc11{};
    #pragma unroll 4
    for (int kk = 0; kk < DMODEL; kk += 32) {
        int k = kk + lg * 8;
        size_t aoff = (size_t)(k >> 6) * HSTRIDE + (k & 63);
        short8 a0 = *(const short8*)(Ah + rb0 + aoff);
        short8 a1 = *(const short8*)(Ah + rb1 + aoff);
        int ko = (kk >> 3) + lg;
        short8 b0 = Br0[ko], b1 = Br1[ko];
        acc00 = __builtin_amdgcn_mfma_f32_16x16x32_bf16(a0, b0, acc00, 0, 0, 0);
        acc01 = __builtin_amdgcn_mfma_f32_16x16x32_bf16(a0, b1, acc01, 0, 0, 0);
        acc10 = __builtin_amdgcn_mfma_f32_16x16x32_bf16(a1, b0, acc10, 0, 0, 0);
        acc11 = __builtin_amdgcn_mfma_f32_16x16x32_bf16(a1, b1, acc11, 0, 0, 0);
    }
    f32x4 accs[2][2] = {{acc00, acc01}, {acc10, acc11}};
    #pragma unroll
    for (int i = 0; i < 2; ++i) {
        #pragma unroll
        for (int j = 0; j < 2; ++j) {
            int n = CB + j * 16 + lm;
            #pragma unroll
            for (int r = 0; r < 4; ++r) {
                int m = RB + i * 16 + lg * 4 + r;
                size_t idx = (size_t)m * DMODEL + n;
                out[idx] = accs[i][j][r] + resid[idx];
            }
        }
    }
}

// ---------- host launch ----------
extern "C" void kernel_launch(void* const* d_in, const int* in_sizes, int n_in,
                              void* d_out, int out_size, void* d_ws, size_t ws_size,
                              hipStream_t stream) {
    const float* q     = (const float*)d_in[0];
    const float* k     = (const float*)d_in[1];
    const float* v     = (const float*)d_in[2];
    const int*   mask  = (const int*)d_in[3];
    const float* Wq    = (const float*)d_in[4];
    const float* Wk    = (const float*)d_in[5];
    const float* Wv    = (const float*)d_in[6];
    const float* Wfc   = (const float*)d_in[7];
    const float* gamma = (const float*)d_in[8];
    const float* beta  = (const float*)d_in[9];
    float* out = (float*)d_out;

    char* ws = (char*)d_ws;
    const size_t SZ_ROWS = (size_t)ROWS * DMODEL * sizeof(short);   // 8 MB
    const size_t SZ_W    = (size_t)DMODEL * DMODEL * sizeof(short); // 512 KB
    short* qn   = (short*)(ws);
    short* kbf  = (short*)(ws + SZ_ROWS);
    short* vbf  = (short*)(ws + 2 * SZ_ROWS);
    short* Wqt  = (short*)(ws + 3 * SZ_ROWS);
    short* Wkt  = (short*)(ws + 3 * SZ_ROWS + SZ_W);
    short* Wvt  = (short*)(ws + 3 * SZ_ROWS + 2 * SZ_W);
    short* Wfct = (short*)(ws + 3 * SZ_ROWS + 3 * SZ_W);
    short* qhb  = (short*)(ws + 3 * SZ_ROWS + 4 * SZ_W);
    short* khb  = (short*)(ws + 4 * SZ_ROWS + 4 * SZ_W);
    short* vhb  = (short*)(ws + 5 * SZ_ROWS + 4 * SZ_W);
    short* aout = qn;  // qn is dead after projections; reuse for attention output

    ln_cast_kernel<<<ROWS / 4, 256, 0, stream>>>(q, gamma, beta, qn);
    cast_bf16_kernel<<<ROWS * DMODEL / (256 * 8), 256, 0, stream>>>(k, kbf);
    cast_bf16_kernel<<<ROWS * DMODEL / (256 * 8), 256, 0, stream>>>(v, vbf);
    castWT_kernel<<<DMODEL * DMODEL / 256, 256, 0, stream>>>(Wq, Wqt);
    castWT_kernel<<<DMODEL * DMODEL / 256, 256, 0, stream>>>(Wk, Wkt);
    castWT_kernel<<<DMODEL * DMODEL / 256, 256, 0, stream>>>(Wv, Wvt);
    castWT_kernel<<<DMODEL * DMODEL / 256, 256, 0, stream>>>(Wfc, Wfct);

    dim3 pgrid(ROWS / 64, DMODEL / 64);
    proj_kernel<<<pgrid, 256, 0, stream>>>(qn,  Wqt, qhb, 0.125f);  // 1/sqrt(64)
    proj_kernel<<<pgrid, 256, 0, stream>>>(kbf, Wkt, khb, 1.0f);
    proj_kernel<<<pgrid, 256, 0, stream>>>(vbf, Wvt, vhb, 1.0f);

    dim3 agrid(SEQ / 64, BH);
    attn_kernel<<<agrid, 256, 0, stream>>>(qhb, khb, vhb, mask, aout);

    dim3 ogrid(ROWS / 64, DMODEL / 64);
    outproj_kernel<<<ogrid, 256, 0, stream>>>(aout, Wfct, q, out);
}